// Round 5
// baseline (69239.502 us; speedup 1.0000x reference)
//
#include <hip/hip_runtime.h>
#include <hip/hip_bf16.h>
#include <stdint.h>

typedef unsigned short u16;
typedef __bf16 bf16x8v __attribute__((ext_vector_type(8)));
typedef float f32x4 __attribute__((ext_vector_type(4)));

#define B_ 16
#define S_ 128
#define T1_ 127
#define E_ 512
#define H_ 1024
#define H4_ 4096
#define V_ 32000
#define NEGBIG -1e10f
#define NBLK 512

__device__ __forceinline__ u16 f2bf(float f) {
    union { float f; unsigned u; } v; v.f = f;
    unsigned u = v.u;
    unsigned r = (u + 0x7fffu + ((u >> 16) & 1u)) >> 16;
    return (u16)r;
}
__device__ __forceinline__ float bf2f(u16 h) {
    union { unsigned u; float f; } v; v.u = ((unsigned)h) << 16;
    return v.f;
}
__device__ __forceinline__ float sigm(float x) { return 1.f / (1.f + expf(-x)); }
__device__ __forceinline__ float dot4(float4 a, float4 b) {
    return a.x * b.x + a.y * b.y + a.z * b.z + a.w * b.w;
}

// ---- grid barrier: per-block 64B-strided flags, block 0 coordinates ----
// arrive[i*16], rel[i*16]; AGENT-scope acq/rel gives cross-XCD visibility.
__device__ __forceinline__ void gbar(int* arrive, int* rel, int ep, int bk) {
    __syncthreads();
    const int tid = threadIdx.x;
    if (bk == 0) {
        if (tid < 64) {
            for (int i = tid; i < NBLK; i += 64) {
                if (i == 0) continue;
                while (__hip_atomic_load(&arrive[i * 16], __ATOMIC_ACQUIRE,
                                         __HIP_MEMORY_SCOPE_AGENT) < ep)
                    __builtin_amdgcn_s_sleep(1);
            }
            for (int i = tid; i < NBLK; i += 64)
                __hip_atomic_store(&rel[i * 16], ep, __ATOMIC_RELEASE,
                                   __HIP_MEMORY_SCOPE_AGENT);
        }
        __syncthreads();
    } else {
        if (tid == 0) {
            __hip_atomic_store(&arrive[bk * 16], ep, __ATOMIC_RELEASE,
                               __HIP_MEMORY_SCOPE_AGENT);
            while (__hip_atomic_load(&rel[bk * 16], __ATOMIC_ACQUIRE,
                                     __HIP_MEMORY_SCOPE_AGENT) < ep)
                __builtin_amdgcn_s_sleep(1);
        }
        __syncthreads();
    }
}

// ---------------- converts / gathers (verified) ----------------

__global__ __launch_bounds__(256) void f32_to_bf16_k(const float* __restrict__ src,
                                                     u16* __restrict__ dst, int n4) {
    int idx = blockIdx.x * 256 + threadIdx.x;
    if (idx >= n4) return;
    float4 v = ((const float4*)src)[idx];
    unsigned lo = (unsigned)f2bf(v.x) | ((unsigned)f2bf(v.y) << 16);
    unsigned hi = (unsigned)f2bf(v.z) | ((unsigned)f2bf(v.w) << 16);
    uint2 pk; pk.x = lo; pk.y = hi;
    *(uint2*)(dst + (size_t)idx * 4) = pk;
}

__global__ __launch_bounds__(128) void split3_rows_k(const float* __restrict__ src,
                                                     int srcStride,
                                                     u16* __restrict__ dst, int nrows,
                                                     int offH2, int offLo) {
    int j = blockIdx.x;
    if (j >= nrows) return;
    int tid = threadIdx.x;
    float4 v = *(const float4*)(src + (size_t)j * srcStride + tid * 4);
    u16 h0 = f2bf(v.x), h1 = f2bf(v.y), h2 = f2bf(v.z), h3 = f2bf(v.w);
    u16 l0 = f2bf(v.x - bf2f(h0)), l1 = f2bf(v.y - bf2f(h1));
    u16 l2 = f2bf(v.z - bf2f(h2)), l3 = f2bf(v.w - bf2f(h3));
    uint2 ph; ph.x = (unsigned)h0 | ((unsigned)h1 << 16); ph.y = (unsigned)h2 | ((unsigned)h3 << 16);
    uint2 pl; pl.x = (unsigned)l0 | ((unsigned)l1 << 16); pl.y = (unsigned)l2 | ((unsigned)l3 << 16);
    u16* base = dst + (size_t)j * 1536 + tid * 4;
    *(uint2*)(base) = ph;
    *(uint2*)(base + offH2) = ph;
    *(uint2*)(base + offLo) = pl;
}

__global__ __launch_bounds__(128) void gather_split_k(const int* __restrict__ toks,
                                                      const float* __restrict__ emb,
                                                      u16* __restrict__ A, int nrows) {
    int m = blockIdx.x;
    if (m >= nrows) return;
    int tIdx = m >> 4, b = m & 15;
    int tok = toks[b * 128 + tIdx];
    int tid = threadIdx.x;
    float4 v = *(const float4*)(emb + (size_t)tok * E_ + tid * 4);
    u16 h0 = f2bf(v.x), h1 = f2bf(v.y), h2 = f2bf(v.z), h3 = f2bf(v.w);
    u16 l0 = f2bf(v.x - bf2f(h0)), l1 = f2bf(v.y - bf2f(h1));
    u16 l2 = f2bf(v.z - bf2f(h2)), l3 = f2bf(v.w - bf2f(h3));
    uint2 ph; ph.x = (unsigned)h0 | ((unsigned)h1 << 16); ph.y = (unsigned)h2 | ((unsigned)h3 << 16);
    uint2 pl; pl.x = (unsigned)l0 | ((unsigned)l1 << 16); pl.y = (unsigned)l2 | ((unsigned)l3 << 16);
    u16* base = A + (size_t)m * 1536 + tid * 4;
    *(uint2*)(base) = ph;
    *(uint2*)(base + 512) = ph;
    *(uint2*)(base + 1024) = pl;
}

// zero state (48K floats) + barrier flags (32K ints) + compute mask2
__global__ __launch_bounds__(256) void init_k(float* __restrict__ zero1,
                                              int* __restrict__ zero2,
                                              const int* __restrict__ mask,
                                              int* __restrict__ mask2) {
    int idx = blockIdx.x * 256 + threadIdx.x;
    float4 z = {0.f, 0.f, 0.f, 0.f};
    if (idx < 12288) ((float4*)zero1)[idx] = z;
    if (idx < 8192) { int4 zi = {0, 0, 0, 0}; ((int4*)zero2)[idx] = zi; }
    if (blockIdx.x == 0 && threadIdx.x < 16) {
        int b = threadIdx.x;
        int first0 = 128;
        for (int s = 0; s < 128; ++s) {
            if (mask[b * 128 + s] == 0) { first0 = s; break; }
        }
        if (first0 == 128) first0 = 0;
        int len = first0 - 1;
        int ix = (len < 0) ? 127 : len;
        for (int s = 0; s < 128; ++s) mask2[b * 128 + s] = mask[b * 128 + s];
        mask2[b * 128 + ix] = 0;
    }
}

// ---------------- bf16 MFMA GEMM (verified) ----------------

#define GLD_LDS(g, l) \
    __builtin_amdgcn_global_load_lds((const __attribute__((address_space(1))) void*)(g), \
                                     (__attribute__((address_space(3))) void*)(l), 16, 0, 0)

template <int MODE>
__global__ __launch_bounds__(256) void gemm_bt(const u16* __restrict__ A,
                                               const u16* __restrict__ Bt,
                                               float* __restrict__ C,
                                               const float* __restrict__ bias1,
                                               const float* __restrict__ bias2,
                                               int M, int N, int K) {
    __shared__ u16 As[128 * 32];
    __shared__ u16 Bs[128 * 32];
    const int tid = threadIdx.x;
    const int bm = blockIdx.x, bn = blockIdx.y;
    const int lane = tid & 63, w = tid >> 6;
    const int wm = (w >> 1) * 64, wn = (w & 1) * 64;
    f32x4 acc[4][4] = {};

    const int r0 = tid >> 2;
    const int c0 = (tid & 3) * 8;
    const u16* ga0 = A + (size_t)(bm * 128 + r0) * K + c0;
    const u16* ga1 = A + (size_t)(bm * 128 + 64 + r0) * K + c0;
    const u16* gb0 = Bt + (size_t)(bn * 128 + r0) * K + c0;
    const u16* gb1 = Bt + (size_t)(bn * 128 + 64 + r0) * K + c0;
    u16* lA0 = As + tid * 8;
    u16* lA1 = As + 2048 + tid * 8;
    u16* lB0 = Bs + tid * 8;
    u16* lB1 = Bs + 2048 + tid * 8;

    const int fl = lane & 15, kg = lane >> 4;

    for (int k0 = 0; k0 < K; k0 += 32) {
        __syncthreads();
        GLD_LDS(ga0 + k0, lA0);
        GLD_LDS(ga1 + k0, lA1);
        GLD_LDS(gb0 + k0, lB0);
        GLD_LDS(gb1 + k0, lB1);
        __syncthreads();
        bf16x8v af[4], bfv[4];
#pragma unroll
        for (int i = 0; i < 4; ++i)
            af[i] = *(const bf16x8v*)(As + (wm + i * 16 + fl) * 32 + kg * 8);
#pragma unroll
        for (int j = 0; j < 4; ++j)
            bfv[j] = *(const bf16x8v*)(Bs + (wn + j * 16 + fl) * 32 + kg * 8);
#pragma unroll
        for (int i = 0; i < 4; ++i)
#pragma unroll
            for (int j = 0; j < 4; ++j)
                acc[i][j] = __builtin_amdgcn_mfma_f32_16x16x32_bf16(af[i], bfv[j], acc[i][j], 0, 0, 0);
    }

    const int coll = lane & 15;
    const int rowb = (lane >> 4) * 4;
#pragma unroll
    for (int i = 0; i < 4; ++i) {
#pragma unroll
        for (int j = 0; j < 4; ++j) {
#pragma unroll
            for (int r = 0; r < 4; ++r) {
                int m = bm * 128 + wm + i * 16 + rowb + r;
                int n = bn * 128 + wn + j * 16 + coll;
                float v = acc[i][j][r];
                if (MODE == 0) {
                    if (m < M) C[(size_t)m * N + n] = v + bias1[n] + bias2[n];
                } else {
                    int tt = m >> 4, bb = m & 15;
                    if (tt < T1_) C[((size_t)bb * T1_ + tt) * V_ + n] = v + bias1[n];
                }
            }
        }
    }
}

// ---------------- persistent encoder: 512 blocks x 256 thr, 2 d per block ----
// LDS ~70.6KB -> exactly 2 blocks/CU; grid 512 = 2x256 CUs -> all resident.

__global__ __launch_bounds__(256, 2) void enc_persist(
    const float* __restrict__ pre, const float* __restrict__ Whh,
    float* __restrict__ h0buf, float* __restrict__ h1buf,
    float* __restrict__ c, float* __restrict__ enc_out,
    int* arrive, int* rel) {
    __shared__ float4 red4[4 * 64 * 17];
    __shared__ float zred[256];
    const int bk = blockIdx.x;
    const int tid = threadIdx.x;
    const int wv = tid >> 6, lane = tid & 63;
    const int k0 = wv * 256 + lane * 4;

    float4 wr[2][4];
#pragma unroll
    for (int dd = 0; dd < 2; ++dd) {
        int d = (bk << 1) + dd;
#pragma unroll
        for (int g = 0; g < 4; ++g)
            wr[dd][g] = *(const float4*)(Whh + (size_t)(g * 1024 + d) * H_ + k0);
    }

    int ep = 0;
    for (int t = 0; t < 128; ++t) {
        const float* h_in = (t & 1) ? h1buf : h0buf;
        float* h_out = (t & 1) ? h0buf : h1buf;
        for (int dd = 0; dd < 2; ++dd) {
            const int d = (bk << 1) + dd;
            float4 part[16];
#pragma unroll
            for (int b = 0; b < 16; ++b) {
                float4 hv = *(const float4*)(h_in + b * H_ + k0);
                part[b].x = dot4(wr[dd][0], hv);
                part[b].y = dot4(wr[dd][1], hv);
                part[b].z = dot4(wr[dd][2], hv);
                part[b].w = dot4(wr[dd][3], hv);
            }
#pragma unroll
            for (int b = 0; b < 16; ++b) red4[(wv * 64 + lane) * 17 + b] = part[b];
            __syncthreads();
            {
                int v = tid & 63, wq = tid >> 6;
                const float* rf = (const float*)red4;
                float s = 0.f;
#pragma unroll 8
                for (int l = 0; l < 64; ++l) s += rf[(wq * 64 + l) * 68 + v];
                zred[wq * 64 + v] = s;
            }
            __syncthreads();
            if (tid < 16) {
                int b = tid;
                float zz[4];
#pragma unroll
                for (int g = 0; g < 4; ++g) {
                    float s = zred[b * 4 + g] + zred[64 + b * 4 + g] +
                              zred[128 + b * 4 + g] + zred[192 + b * 4 + g];
                    zz[g] = s + pre[(size_t)(t * 16 + b) * H4_ + g * 1024 + d];
                }
                float co = c[b * H_ + d];
                float c2 = sigm(zz[1]) * co + sigm(zz[0]) * tanhf(zz[2]);
                float h2 = sigm(zz[3]) * tanhf(c2);
                c[b * H_ + d] = c2;
                h_out[b * H_ + d] = h2;
                enc_out[((size_t)b * 128 + t) * H_ + d] = h2;
            }
        }
        gbar(arrive, rel, ++ep, bk);
    }
}

// ---------------- persistent decoder: 3 phases per step ----------------
// LDS ~73.5KB -> 2 blocks/CU; grid 512 -> all resident.

__global__ __launch_bounds__(256, 2) void dec_persist(
    const float* __restrict__ pre, const float* __restrict__ Whh,
    const float* __restrict__ WihFull, const float* __restrict__ attn_W,
    const float* __restrict__ attn_b,
    float* __restrict__ h0buf, float* __restrict__ h1buf,
    float* __restrict__ a0buf, float* __restrict__ a1buf,
    float* __restrict__ c, const float* __restrict__ enc_out,
    const int* __restrict__ mask2, float* __restrict__ ct,
    u16* __restrict__ a2bf, int* arrive, int* rel) {
    __shared__ float4 red4[4 * 64 * 17];
    __shared__ float zred[256];
    __shared__ float hq[1024];
    __shared__ float ps[128];
    __shared__ float red[2];
    const int bk = blockIdx.x;
    const int tid = threadIdx.x;
    const int wv = tid >> 6, lane = tid & 63;
    const int kq = (wv & 1) * 512 + lane * 8;
    const bool isA = wv >= 2;  // LSTM: waves 2,3 do the a-side
    const bool isH = wv >= 2;  // a2: waves 2,3 do the h-side

    // preload LSTM weights (2 d x 4 gates x 2 float4)
    float4 wr[2][4][2];
#pragma unroll
    for (int dd = 0; dd < 2; ++dd) {
        int d = (bk << 1) + dd;
#pragma unroll
        for (int g = 0; g < 4; ++g) {
            int j = g * 1024 + d;
            const float* wsrc = isA ? (WihFull + (size_t)j * 1536 + 512 + kq)
                                    : (Whh + (size_t)j * H_ + kq);
            wr[dd][g][0] = *(const float4*)(wsrc);
            wr[dd][g][1] = *(const float4*)(wsrc + 4);
        }
    }
    // preload a2 weights (2 d x 2 float4)
    float4 wa2[2][2];
#pragma unroll
    for (int dd = 0; dd < 2; ++dd) {
        int d = (bk << 1) + dd;
        const float* wsrc = attn_W + (size_t)d * 2048 + (isH ? 1024 : 0) + kq;
        wa2[dd][0] = *(const float4*)(wsrc);
        wa2[dd][1] = *(const float4*)(wsrc + 4);
    }

    int ep = 0;
    for (int t = 0; t < T1_; ++t) {
        const float* h_in = (t & 1) ? h1buf : h0buf;
        float* h_out = (t & 1) ? h0buf : h1buf;
        const float* a_in = (t & 1) ? a1buf : a0buf;
        float* a_out = (t & 1) ? a0buf : a1buf;

        // ---- phase 1: LSTM for my 2 d ----
        const float* xsrc1 = isA ? a_in : h_in;
        for (int dd = 0; dd < 2; ++dd) {
            const int d = (bk << 1) + dd;
            float4 part[16];
#pragma unroll
            for (int b = 0; b < 16; ++b) {
                float4 x0 = *(const float4*)(xsrc1 + b * H_ + kq);
                float4 x1 = *(const float4*)(xsrc1 + b * H_ + kq + 4);
                part[b].x = dot4(wr[dd][0][0], x0) + dot4(wr[dd][0][1], x1);
                part[b].y = dot4(wr[dd][1][0], x0) + dot4(wr[dd][1][1], x1);
                part[b].z = dot4(wr[dd][2][0], x0) + dot4(wr[dd][2][1], x1);
                part[b].w = dot4(wr[dd][3][0], x0) + dot4(wr[dd][3][1], x1);
            }
#pragma unroll
            for (int b = 0; b < 16; ++b) red4[(wv * 64 + lane) * 17 + b] = part[b];
            __syncthreads();
            {
                int v = tid & 63, wq = tid >> 6;
                const float* rf = (const float*)red4;
                float s = 0.f;
#pragma unroll 8
                for (int l = 0; l < 64; ++l) s += rf[(wq * 64 + l) * 68 + v];
                zred[wq * 64 + v] = s;
            }
            __syncthreads();
            if (tid < 16) {
                int b = tid;
                float zz[4];
#pragma unroll
                for (int g = 0; g < 4; ++g) {
                    float s = zred[b * 4 + g] + zred[64 + b * 4 + g] +
                              zred[128 + b * 4 + g] + zred[192 + b * 4 + g];
                    zz[g] = s + pre[(size_t)(t * 16 + b) * H4_ + g * 1024 + d];
                }
                float co = c[b * H_ + d];
                float c2 = sigm(zz[1]) * co + sigm(zz[0]) * tanhf(zz[2]);
                float h2 = sigm(zz[3]) * tanhf(c2);
                c[b * H_ + d] = c2;
                h_out[b * H_ + d] = h2;
            }
            __syncthreads();
        }
        gbar(arrive, rel, ++ep, bk);

        // ---- phase 2: attention (blocks 0..15, one per b) ----
        if (bk < 16) {
            int b = bk;
            *(float4*)(hq + tid * 4) = *(const float4*)(h_out + b * H_ + tid * 4);
            __syncthreads();
            int s = tid >> 1, hf = tid & 1;
            const float* er = enc_out + ((size_t)b * 128 + s) * H_ + hf * 512;
            const float* hr = hq + hf * 512;
            float sc = 0.f;
            for (int k = 0; k < 512; k += 4) {
                float4 e = *(const float4*)(er + k);
                sc += e.x * hr[k] + e.y * hr[k + 1] + e.z * hr[k + 2] + e.w * hr[k + 3];
            }
            sc += __shfl_xor(sc, 1);
            if (hf == 0) ps[s] = (mask2[b * 128 + s] == 1) ? NEGBIG : sc;
            __syncthreads();
            if (tid < 64) {
                float m2 = fmaxf(ps[tid], ps[tid + 64]);
                for (int off = 32; off; off >>= 1) m2 = fmaxf(m2, __shfl_xor(m2, off));
                if (tid == 0) red[0] = m2;
            }
            __syncthreads();
            if (tid < 128) ps[tid] = expf(ps[tid] - red[0]);
            __syncthreads();
            if (tid < 64) {
                float s2 = ps[tid] + ps[tid + 64];
                for (int off = 32; off; off >>= 1) s2 += __shfl_xor(s2, off);
                if (tid == 0) red[1] = 1.f / s2;
            }
            __syncthreads();
            float inv = red[1];
            int d0 = tid * 4;
            float4 av = {0.f, 0.f, 0.f, 0.f};
            for (int s2 = 0; s2 < 128; ++s2) {
                float p = ps[s2] * inv;
                float4 e = *(const float4*)(enc_out + ((size_t)b * 128 + s2) * H_ + d0);
                av.x += p * e.x; av.y += p * e.y; av.z += p * e.z; av.w += p * e.w;
            }
            *(float4*)(ct + b * H_ + d0) = av;
        }
        gbar(arrive, rel, ++ep, bk);

        // ---- phase 3: a2 for my 2 d ----
        const float* xsrc3 = isH ? h_out : ct;
        for (int dd = 0; dd < 2; ++dd) {
            const int d = (bk << 1) + dd;
            float partA[16];
#pragma unroll
            for (int b = 0; b < 16; ++b) {
                float4 x0 = *(const float4*)(xsrc3 + b * H_ + kq);
                float4 x1 = *(const float4*)(xsrc3 + b * H_ + kq + 4);
                partA[b] = dot4(wa2[dd][0], x0) + dot4(wa2[dd][1], x1);
            }
#pragma unroll
            for (int q = 0; q < 4; ++q)
                red4[(wv * 64 + lane) * 17 + q] =
                    make_float4(partA[q * 4], partA[q * 4 + 1], partA[q * 4 + 2], partA[q * 4 + 3]);
            __syncthreads();
            if (tid < 64) {
                int v = tid & 15, wq = tid >> 4;
                const float* rf = (const float*)red4;
                float s = 0.f;
#pragma unroll 8
                for (int l = 0; l < 64; ++l) s += rf[(wq * 64 + l) * 68 + v];
                zred[wq * 16 + v] = s;
            }
            __syncthreads();
            if (tid < 16) {
                int b = tid;
                float v = zred[b] + zred[16 + b] + zred[32 + b] + zred[48 + b] + attn_b[d];
                v = tanhf(v);
                a_out[b * H_ + d] = v;
                a2bf[((size_t)(t * 16 + b)) * H_ + d] = f2bf(v);
            }
            __syncthreads();
        }
        gbar(arrive, rel, ++ep, bk);
    }
}

// ---------------- orchestration ----------------

extern "C" void kernel_launch(void* const* d_in, const int* in_sizes, int n_in,
                              void* d_out, int out_size, void* d_ws, size_t ws_size,
                              hipStream_t stream) {
    const int* in_tok = (const int*)d_in[0];
    const int* out_tok = (const int*)d_in[1];
    const int* mask = (const int*)d_in[2];
    const float* emb_in = (const float*)d_in[3];
    const float* emb_out = (const float*)d_in[4];
    const float* enc_Wih = (const float*)d_in[5];
    const float* enc_Whh = (const float*)d_in[6];
    const float* enc_bih = (const float*)d_in[7];
    const float* enc_bhh = (const float*)d_in[8];
    const float* dec_Wih = (const float*)d_in[9];
    const float* dec_Whh = (const float*)d_in[10];
    const float* dec_bih = (const float*)d_in[11];
    const float* dec_bhh = (const float*)d_in[12];
    const float* attn_W = (const float*)d_in[13];
    const float* attn_b = (const float*)d_in[14];
    const float* out_W = (const float*)d_in[15];
    const float* out_b = (const float*)d_in[16];
    float* out = (float*)d_out;

    char* p = (char*)d_ws;
    auto alloc = [&](size_t bytes) {
        char* r = p;
        p += (bytes + 255) & ~(size_t)255;
        return r;
    };
    u16* A_enc3 = (u16*)alloc((size_t)2048 * 1536 * 2);
    u16* A_dec3 = (u16*)alloc((size_t)2048 * 1536 * 2);
    u16* W_e3 = (u16*)alloc((size_t)4096 * 1536 * 2);
    u16* W_d3 = (u16*)alloc((size_t)4096 * 1536 * 2);
    u16* Wo = (u16*)alloc((size_t)32000 * 1024 * 2);
    float* enc_pre = (float*)alloc((size_t)2048 * 4096 * 4);
    float* dec_pre = (float*)alloc((size_t)2048 * 4096 * 4);
    float* enc_out = (float*)alloc((size_t)16 * 128 * 1024 * 4);
    u16* a2bf = (u16*)alloc((size_t)2048 * 1024 * 2);
    // zeroed state: h0 | c | a0 (3 x 16K floats contiguous)
    float* h0 = (float*)alloc(16 * 1024 * 4);
    float* c = (float*)alloc(16 * 1024 * 4);
    float* a0 = (float*)alloc(16 * 1024 * 4);
    float* h1 = (float*)alloc(16 * 1024 * 4);
    float* a1 = (float*)alloc(16 * 1024 * 4);
    float* ct = (float*)alloc(16 * 1024 * 4);
    // zeroed barrier flags: arrE | relE | arrD | relD (4 x 512 x 16 ints contiguous)
    int* barE_a = (int*)alloc((size_t)512 * 16 * 4);
    int* barE_r = (int*)alloc((size_t)512 * 16 * 4);
    int* barD_a = (int*)alloc((size_t)512 * 16 * 4);
    int* barD_r = (int*)alloc((size_t)512 * 16 * 4);
    int* mask2 = (int*)alloc(16 * 128 * 4);

    init_k<<<48, 256, 0, stream>>>(h0, barE_a, mask, mask2);

    split3_rows_k<<<4096, 128, 0, stream>>>(enc_Wih, 512, W_e3, 4096, 1024, 512);
    split3_rows_k<<<4096, 128, 0, stream>>>(dec_Wih, 1536, W_d3, 4096, 1024, 512);
    f32_to_bf16_k<<<32000, 256, 0, stream>>>(out_W, Wo, 32000 * 1024 / 4);
    gather_split_k<<<2048, 128, 0, stream>>>(in_tok, emb_in, A_enc3, 2048);
    gather_split_k<<<2032, 128, 0, stream>>>(out_tok, emb_out, A_dec3, 2032);

    gemm_bt<0><<<dim3(16, 32), 256, 0, stream>>>(A_enc3, W_e3, enc_pre, enc_bih, enc_bhh,
                                                 2048, 4096, 1536);
    gemm_bt<0><<<dim3(16, 32), 256, 0, stream>>>(A_dec3, W_d3, dec_pre, dec_bih, dec_bhh,
                                                 2048, 4096, 1536);

    enc_persist<<<512, 256, 0, stream>>>(enc_pre, enc_Whh, h0, h1, c, enc_out,
                                         barE_a, barE_r);

    dec_persist<<<512, 256, 0, stream>>>(dec_pre, dec_Whh, dec_Wih, attn_W, attn_b,
                                         h0, h1, a0, a1, c, enc_out, mask2, ct, a2bf,
                                         barD_a, barD_r);

    gemm_bt<1><<<dim3(16, 250), 256, 0, stream>>>(a2bf, Wo, out, out_b, nullptr,
                                                  2048, 32000, 1024);
}

// Round 6
// 7554.107 us; speedup vs baseline: 9.1658x; 9.1658x over previous
//
#include <hip/hip_runtime.h>
#include <hip/hip_bf16.h>
#include <stdint.h>

typedef unsigned short u16;
typedef __bf16 bf16x8v __attribute__((ext_vector_type(8)));
typedef float f32x4 __attribute__((ext_vector_type(4)));

#define B_ 16
#define S_ 128
#define T1_ 127
#define E_ 512
#define H_ 1024
#define H4_ 4096
#define V_ 32000
#define NEGBIG -1e10f
#define NBLK 512

__device__ __forceinline__ u16 f2bf(float f) {
    union { float f; unsigned u; } v; v.f = f;
    unsigned u = v.u;
    unsigned r = (u + 0x7fffu + ((u >> 16) & 1u)) >> 16;
    return (u16)r;
}
__device__ __forceinline__ float bf2f(u16 h) {
    union { unsigned u; float f; } v; v.u = ((unsigned)h) << 16;
    return v.f;
}
__device__ __forceinline__ float sigm(float x) { return 1.f / (1.f + expf(-x)); }
__device__ __forceinline__ float dot4(float4 a, float4 b) {
    return a.x * b.x + a.y * b.y + a.z * b.z + a.w * b.w;
}

// Cross-block publish: device-scope RMW (coherent across XCDs, no cache flushes).
__device__ __forceinline__ void pubf(float* p, float v) { atomicExch(p, v); }

// ---- grid barrier: RMW-only flags, no acquire/release fences ----
// Writer protocol: drain own stores (vmcnt), then atomicExch arrive flag.
// Reader protocol: poll via atomicAdd(p,0) RMW (always reads coherence point).
__device__ __forceinline__ void gbar(int* arrive, int* rel, int ep, int bk) {
    asm volatile("s_waitcnt vmcnt(0) lgkmcnt(0)" ::: "memory");
    __syncthreads();
    const int tid = threadIdx.x;
    if (bk == 0) {
        if (tid < 64) {
            for (int i = tid; i < NBLK; i += 64) {
                if (i == 0) continue;
                while (atomicAdd(&arrive[i * 16], 0) < ep) __builtin_amdgcn_s_sleep(1);
            }
            for (int i = tid; i < NBLK; i += 64) atomicExch(&rel[i * 16], ep);
        }
        __syncthreads();
    } else {
        if (tid == 0) {
            atomicExch(&arrive[bk * 16], ep);
            while (atomicAdd(&rel[bk * 16], 0) < ep) __builtin_amdgcn_s_sleep(1);
        }
        __syncthreads();
    }
}

// ---------------- converts / gathers (verified) ----------------

__global__ __launch_bounds__(256) void f32_to_bf16_k(const float* __restrict__ src,
                                                     u16* __restrict__ dst, int n4) {
    int idx = blockIdx.x * 256 + threadIdx.x;
    if (idx >= n4) return;
    float4 v = ((const float4*)src)[idx];
    unsigned lo = (unsigned)f2bf(v.x) | ((unsigned)f2bf(v.y) << 16);
    unsigned hi = (unsigned)f2bf(v.z) | ((unsigned)f2bf(v.w) << 16);
    uint2 pk; pk.x = lo; pk.y = hi;
    *(uint2*)(dst + (size_t)idx * 4) = pk;
}

__global__ __launch_bounds__(128) void split3_rows_k(const float* __restrict__ src,
                                                     int srcStride,
                                                     u16* __restrict__ dst, int nrows,
                                                     int offH2, int offLo) {
    int j = blockIdx.x;
    if (j >= nrows) return;
    int tid = threadIdx.x;
    float4 v = *(const float4*)(src + (size_t)j * srcStride + tid * 4);
    u16 h0 = f2bf(v.x), h1 = f2bf(v.y), h2 = f2bf(v.z), h3 = f2bf(v.w);
    u16 l0 = f2bf(v.x - bf2f(h0)), l1 = f2bf(v.y - bf2f(h1));
    u16 l2 = f2bf(v.z - bf2f(h2)), l3 = f2bf(v.w - bf2f(h3));
    uint2 ph; ph.x = (unsigned)h0 | ((unsigned)h1 << 16); ph.y = (unsigned)h2 | ((unsigned)h3 << 16);
    uint2 pl; pl.x = (unsigned)l0 | ((unsigned)l1 << 16); pl.y = (unsigned)l2 | ((unsigned)l3 << 16);
    u16* base = dst + (size_t)j * 1536 + tid * 4;
    *(uint2*)(base) = ph;
    *(uint2*)(base + offH2) = ph;
    *(uint2*)(base + offLo) = pl;
}

__global__ __launch_bounds__(128) void gather_split_k(const int* __restrict__ toks,
                                                      const float* __restrict__ emb,
                                                      u16* __restrict__ A, int nrows) {
    int m = blockIdx.x;
    if (m >= nrows) return;
    int tIdx = m >> 4, b = m & 15;
    int tok = toks[b * 128 + tIdx];
    int tid = threadIdx.x;
    float4 v = *(const float4*)(emb + (size_t)tok * E_ + tid * 4);
    u16 h0 = f2bf(v.x), h1 = f2bf(v.y), h2 = f2bf(v.z), h3 = f2bf(v.w);
    u16 l0 = f2bf(v.x - bf2f(h0)), l1 = f2bf(v.y - bf2f(h1));
    u16 l2 = f2bf(v.z - bf2f(h2)), l3 = f2bf(v.w - bf2f(h3));
    uint2 ph; ph.x = (unsigned)h0 | ((unsigned)h1 << 16); ph.y = (unsigned)h2 | ((unsigned)h3 << 16);
    uint2 pl; pl.x = (unsigned)l0 | ((unsigned)l1 << 16); pl.y = (unsigned)l2 | ((unsigned)l3 << 16);
    u16* base = A + (size_t)m * 1536 + tid * 4;
    *(uint2*)(base) = ph;
    *(uint2*)(base + 512) = ph;
    *(uint2*)(base + 1024) = pl;
}

// zero state (h0|c|a0 = 48K floats) + barrier flags (32K ints) + mask2
__global__ __launch_bounds__(256) void init_k(float* __restrict__ zero1,
                                              int* __restrict__ zero2,
                                              const int* __restrict__ mask,
                                              int* __restrict__ mask2) {
    int idx = blockIdx.x * 256 + threadIdx.x;
    float4 z = {0.f, 0.f, 0.f, 0.f};
    if (idx < 12288) ((float4*)zero1)[idx] = z;
    if (idx < 8192) { int4 zi = {0, 0, 0, 0}; ((int4*)zero2)[idx] = zi; }
    if (blockIdx.x == 0 && threadIdx.x < 16) {
        int b = threadIdx.x;
        int first0 = 128;
        for (int s = 0; s < 128; ++s) {
            if (mask[b * 128 + s] == 0) { first0 = s; break; }
        }
        if (first0 == 128) first0 = 0;
        int len = first0 - 1;
        int ix = (len < 0) ? 127 : len;
        for (int s = 0; s < 128; ++s) mask2[b * 128 + s] = mask[b * 128 + s];
        mask2[b * 128 + ix] = 0;
    }
}

// ---------------- bf16 MFMA GEMM (verified) ----------------

#define GLD_LDS(g, l) \
    __builtin_amdgcn_global_load_lds((const __attribute__((address_space(1))) void*)(g), \
                                     (__attribute__((address_space(3))) void*)(l), 16, 0, 0)

template <int MODE>
__global__ __launch_bounds__(256) void gemm_bt(const u16* __restrict__ A,
                                               const u16* __restrict__ Bt,
                                               float* __restrict__ C,
                                               const float* __restrict__ bias1,
                                               const float* __restrict__ bias2,
                                               int M, int N, int K) {
    __shared__ u16 As[128 * 32];
    __shared__ u16 Bs[128 * 32];
    const int tid = threadIdx.x;
    const int bm = blockIdx.x, bn = blockIdx.y;
    const int lane = tid & 63, w = tid >> 6;
    const int wm = (w >> 1) * 64, wn = (w & 1) * 64;
    f32x4 acc[4][4] = {};

    const int r0 = tid >> 2;
    const int c0 = (tid & 3) * 8;
    const u16* ga0 = A + (size_t)(bm * 128 + r0) * K + c0;
    const u16* ga1 = A + (size_t)(bm * 128 + 64 + r0) * K + c0;
    const u16* gb0 = Bt + (size_t)(bn * 128 + r0) * K + c0;
    const u16* gb1 = Bt + (size_t)(bn * 128 + 64 + r0) * K + c0;
    u16* lA0 = As + tid * 8;
    u16* lA1 = As + 2048 + tid * 8;
    u16* lB0 = Bs + tid * 8;
    u16* lB1 = Bs + 2048 + tid * 8;

    const int fl = lane & 15, kg = lane >> 4;

    for (int k0 = 0; k0 < K; k0 += 32) {
        __syncthreads();
        GLD_LDS(ga0 + k0, lA0);
        GLD_LDS(ga1 + k0, lA1);
        GLD_LDS(gb0 + k0, lB0);
        GLD_LDS(gb1 + k0, lB1);
        __syncthreads();
        bf16x8v af[4], bfv[4];
#pragma unroll
        for (int i = 0; i < 4; ++i)
            af[i] = *(const bf16x8v*)(As + (wm + i * 16 + fl) * 32 + kg * 8);
#pragma unroll
        for (int j = 0; j < 4; ++j)
            bfv[j] = *(const bf16x8v*)(Bs + (wn + j * 16 + fl) * 32 + kg * 8);
#pragma unroll
        for (int i = 0; i < 4; ++i)
#pragma unroll
            for (int j = 0; j < 4; ++j)
                acc[i][j] = __builtin_amdgcn_mfma_f32_16x16x32_bf16(af[i], bfv[j], acc[i][j], 0, 0, 0);
    }

    const int coll = lane & 15;
    const int rowb = (lane >> 4) * 4;
#pragma unroll
    for (int i = 0; i < 4; ++i) {
#pragma unroll
        for (int j = 0; j < 4; ++j) {
#pragma unroll
            for (int r = 0; r < 4; ++r) {
                int m = bm * 128 + wm + i * 16 + rowb + r;
                int n = bn * 128 + wn + j * 16 + coll;
                float v = acc[i][j][r];
                if (MODE == 0) {
                    if (m < M) C[(size_t)m * N + n] = v + bias1[n] + bias2[n];
                } else {
                    int tt = m >> 4, bb = m & 15;
                    if (tt < T1_) C[((size_t)bb * T1_ + tt) * V_ + n] = v + bias1[n];
                }
            }
        }
    }
}

// ---------------- persistent encoder ----------------
// 512 blocks x 256 thr, 2 d/block, weights in regs. h exchanged through the
// write-once enc_out ring (publish via atomicExch; reads are normal cached
// loads of never-before-touched addresses -> no staleness possible).

__global__ __launch_bounds__(256, 2) void enc_persist(
    const float* __restrict__ pre, const float* __restrict__ Whh,
    const float* __restrict__ h0zero, float* __restrict__ c,
    float* __restrict__ enc_out, int* arrive, int* rel) {
    __shared__ float4 red4[4 * 64 * 17];
    __shared__ float zred[256];
    const int bk = blockIdx.x;
    const int tid = threadIdx.x;
    const int wv = tid >> 6, lane = tid & 63;
    const int k0 = wv * 256 + lane * 4;

    float4 wr[2][4];
#pragma unroll
    for (int dd = 0; dd < 2; ++dd) {
        int d = (bk << 1) + dd;
#pragma unroll
        for (int g = 0; g < 4; ++g)
            wr[dd][g] = *(const float4*)(Whh + (size_t)(g * 1024 + d) * H_ + k0);
    }

    int ep = 0;
    for (int t = 0; t < 128; ++t) {
        const float* xsrc;
        size_t xstr;
        if (t == 0) { xsrc = h0zero; xstr = H_; }
        else { xsrc = enc_out + (size_t)(t - 1) * H_; xstr = (size_t)128 * H_; }

        for (int dd = 0; dd < 2; ++dd) {
            const int d = (bk << 1) + dd;
            float4 part[16];
#pragma unroll
            for (int b = 0; b < 16; ++b) {
                float4 hv = *(const float4*)(xsrc + (size_t)b * xstr + k0);
                part[b].x = dot4(wr[dd][0], hv);
                part[b].y = dot4(wr[dd][1], hv);
                part[b].z = dot4(wr[dd][2], hv);
                part[b].w = dot4(wr[dd][3], hv);
            }
#pragma unroll
            for (int b = 0; b < 16; ++b) red4[(wv * 64 + lane) * 17 + b] = part[b];
            __syncthreads();
            {
                int v = tid & 63, wq = tid >> 6;
                const float* rf = (const float*)red4;
                float s = 0.f;
#pragma unroll 8
                for (int l = 0; l < 64; ++l) s += rf[(wq * 64 + l) * 68 + v];
                zred[wq * 64 + v] = s;
            }
            __syncthreads();
            if (tid < 16) {
                int b = tid;
                float zz[4];
#pragma unroll
                for (int g = 0; g < 4; ++g) {
                    float s = zred[b * 4 + g] + zred[64 + b * 4 + g] +
                              zred[128 + b * 4 + g] + zred[192 + b * 4 + g];
                    zz[g] = s + pre[(size_t)(t * 16 + b) * H4_ + g * 1024 + d];
                }
                float co = c[b * H_ + d];
                float c2 = sigm(zz[1]) * co + sigm(zz[0]) * tanhf(zz[2]);
                float h2 = sigm(zz[3]) * tanhf(c2);
                c[b * H_ + d] = c2;                              // block-private
                pubf(&enc_out[((size_t)b * 128 + t) * H_ + d], h2);  // publish
            }
            __syncthreads();
        }
        gbar(arrive, rel, ++ep, bk);
    }
}

// ---------------- persistent decoder: 3 phases/step, ring-buffered state ----

__global__ __launch_bounds__(256, 2) void dec_persist(
    const float* __restrict__ pre, const float* __restrict__ Whh,
    const float* __restrict__ WihFull, const float* __restrict__ attn_W,
    const float* __restrict__ attn_b, const float* __restrict__ enc_out,
    float* __restrict__ h_ring, float* __restrict__ a_ring,
    float* __restrict__ ct_ring, const float* __restrict__ a0zero,
    float* __restrict__ c, const int* __restrict__ mask2,
    u16* __restrict__ a2bf, int* arrive, int* rel) {
    __shared__ float4 red4[4 * 64 * 17];
    __shared__ float zred[256];
    __shared__ float hq[1024];
    __shared__ float ps[128];
    __shared__ float red[2];
    const int bk = blockIdx.x;
    const int tid = threadIdx.x;
    const int wv = tid >> 6, lane = tid & 63;
    const int kq = (wv & 1) * 512 + lane * 8;
    const bool isA = wv >= 2;  // LSTM: waves 2,3 take the a-side
    const bool isH = wv >= 2;  // a2: waves 2,3 take the h-side

    float4 wr[2][4][2];
#pragma unroll
    for (int dd = 0; dd < 2; ++dd) {
        int d = (bk << 1) + dd;
#pragma unroll
        for (int g = 0; g < 4; ++g) {
            int j = g * 1024 + d;
            const float* wsrc = isA ? (WihFull + (size_t)j * 1536 + 512 + kq)
                                    : (Whh + (size_t)j * H_ + kq);
            wr[dd][g][0] = *(const float4*)(wsrc);
            wr[dd][g][1] = *(const float4*)(wsrc + 4);
        }
    }
    float4 wa2[2][2];
#pragma unroll
    for (int dd = 0; dd < 2; ++dd) {
        int d = (bk << 1) + dd;
        const float* wsrc = attn_W + (size_t)d * 2048 + (isH ? 1024 : 0) + kq;
        wa2[dd][0] = *(const float4*)(wsrc);
        wa2[dd][1] = *(const float4*)(wsrc + 4);
    }

    int ep = 0;
    for (int t = 0; t < T1_; ++t) {
        // x sources for phase 1: h(t-1) and a(t-1)
        const float* hsrc;
        size_t hstr;
        if (t == 0) { hsrc = enc_out + (size_t)127 * H_; hstr = (size_t)128 * H_; }
        else { hsrc = h_ring + (size_t)(t - 1) * B_ * H_; hstr = H_; }
        const float* asrc = (t == 0) ? a0zero : (a_ring + (size_t)(t - 1) * B_ * H_);
        float* hcur = h_ring + (size_t)t * B_ * H_;
        float* ctcur = ct_ring + (size_t)t * B_ * H_;
        float* acur = a_ring + (size_t)t * B_ * H_;

        // ---- phase 1: LSTM for my 2 d ----
        const float* xsrc1 = isA ? asrc : hsrc;
        const size_t xstr1 = isA ? (size_t)H_ : hstr;
        for (int dd = 0; dd < 2; ++dd) {
            const int d = (bk << 1) + dd;
            float4 part[16];
#pragma unroll
            for (int b = 0; b < 16; ++b) {
                float4 x0 = *(const float4*)(xsrc1 + (size_t)b * xstr1 + kq);
                float4 x1 = *(const float4*)(xsrc1 + (size_t)b * xstr1 + kq + 4);
                part[b].x = dot4(wr[dd][0][0], x0) + dot4(wr[dd][0][1], x1);
                part[b].y = dot4(wr[dd][1][0], x0) + dot4(wr[dd][1][1], x1);
                part[b].z = dot4(wr[dd][2][0], x0) + dot4(wr[dd][2][1], x1);
                part[b].w = dot4(wr[dd][3][0], x0) + dot4(wr[dd][3][1], x1);
            }
#pragma unroll
            for (int b = 0; b < 16; ++b) red4[(wv * 64 + lane) * 17 + b] = part[b];
            __syncthreads();
            {
                int v = tid & 63, wq = tid >> 6;
                const float* rf = (const float*)red4;
                float s = 0.f;
#pragma unroll 8
                for (int l = 0; l < 64; ++l) s += rf[(wq * 64 + l) * 68 + v];
                zred[wq * 64 + v] = s;
            }
            __syncthreads();
            if (tid < 16) {
                int b = tid;
                float zz[4];
#pragma unroll
                for (int g = 0; g < 4; ++g) {
                    float s = zred[b * 4 + g] + zred[64 + b * 4 + g] +
                              zred[128 + b * 4 + g] + zred[192 + b * 4 + g];
                    zz[g] = s + pre[(size_t)(t * 16 + b) * H4_ + g * 1024 + d];
                }
                float co = c[b * H_ + d];
                float c2 = sigm(zz[1]) * co + sigm(zz[0]) * tanhf(zz[2]);
                float h2 = sigm(zz[3]) * tanhf(c2);
                c[b * H_ + d] = c2;                 // block-private
                pubf(&hcur[b * H_ + d], h2);        // publish h(t)
            }
            __syncthreads();
        }
        gbar(arrive, rel, ++ep, bk);

        // ---- phase 2: attention (blocks 0..15, one per b) ----
        if (bk < 16) {
            int b = bk;
            *(float4*)(hq + tid * 4) = *(const float4*)(hcur + b * H_ + tid * 4);
            __syncthreads();
            int s = tid >> 1, hf = tid & 1;
            const float* er = enc_out + ((size_t)b * 128 + s) * H_ + hf * 512;
            const float* hr = hq + hf * 512;
            float sc = 0.f;
            for (int k = 0; k < 512; k += 4) {
                float4 e = *(const float4*)(er + k);
                sc += e.x * hr[k] + e.y * hr[k + 1] + e.z * hr[k + 2] + e.w * hr[k + 3];
            }
            sc += __shfl_xor(sc, 1);
            if (hf == 0) ps[s] = (mask2[b * 128 + s] == 1) ? NEGBIG : sc;
            __syncthreads();
            if (tid < 64) {
                float m2 = fmaxf(ps[tid], ps[tid + 64]);
                for (int off = 32; off; off >>= 1) m2 = fmaxf(m2, __shfl_xor(m2, off));
                if (tid == 0) red[0] = m2;
            }
            __syncthreads();
            if (tid < 128) ps[tid] = expf(ps[tid] - red[0]);
            __syncthreads();
            if (tid < 64) {
                float s2 = ps[tid] + ps[tid + 64];
                for (int off = 32; off; off >>= 1) s2 += __shfl_xor(s2, off);
                if (tid == 0) red[1] = 1.f / s2;
            }
            __syncthreads();
            float inv = red[1];
            int d0 = tid * 4;
            float4 av = {0.f, 0.f, 0.f, 0.f};
            for (int s2 = 0; s2 < 128; ++s2) {
                float p = ps[s2] * inv;
                float4 e = *(const float4*)(enc_out + ((size_t)b * 128 + s2) * H_ + d0);
                av.x += p * e.x; av.y += p * e.y; av.z += p * e.z; av.w += p * e.w;
            }
            pubf(&ctcur[b * H_ + d0 + 0], av.x);
            pubf(&ctcur[b * H_ + d0 + 1], av.y);
            pubf(&ctcur[b * H_ + d0 + 2], av.z);
            pubf(&ctcur[b * H_ + d0 + 3], av.w);
        }
        gbar(arrive, rel, ++ep, bk);

        // ---- phase 3: a2 for my 2 d ----
        const float* xsrc3 = isH ? hcur : ctcur;
        for (int dd = 0; dd < 2; ++dd) {
            const int d = (bk << 1) + dd;
            float partA[16];
#pragma unroll
            for (int b = 0; b < 16; ++b) {
                float4 x0 = *(const float4*)(xsrc3 + b * H_ + kq);
                float4 x1 = *(const float4*)(xsrc3 + b * H_ + kq + 4);
                partA[b] = dot4(wa2[dd][0], x0) + dot4(wa2[dd][1], x1);
            }
#pragma unroll
            for (int q = 0; q < 4; ++q)
                red4[(wv * 64 + lane) * 17 + q] =
                    make_float4(partA[q * 4], partA[q * 4 + 1], partA[q * 4 + 2], partA[q * 4 + 3]);
            __syncthreads();
            if (tid < 64) {
                int v = tid & 15, wq = tid >> 4;
                const float* rf = (const float*)red4;
                float s = 0.f;
#pragma unroll 8
                for (int l = 0; l < 64; ++l) s += rf[(wq * 64 + l) * 68 + v];
                zred[wq * 16 + v] = s;
            }
            __syncthreads();
            if (tid < 16) {
                int b = tid;
                float v = zred[b] + zred[16 + b] + zred[32 + b] + zred[48 + b] + attn_b[d];
                v = tanhf(v);
                pubf(&acur[b * H_ + d], v);                       // publish a(t)
                a2bf[((size_t)(t * 16 + b)) * H_ + d] = f2bf(v);  // kernel-local out
            }
            __syncthreads();
        }
        gbar(arrive, rel, ++ep, bk);
    }
}

// ---------------- orchestration ----------------

extern "C" void kernel_launch(void* const* d_in, const int* in_sizes, int n_in,
                              void* d_out, int out_size, void* d_ws, size_t ws_size,
                              hipStream_t stream) {
    const int* in_tok = (const int*)d_in[0];
    const int* out_tok = (const int*)d_in[1];
    const int* mask = (const int*)d_in[2];
    const float* emb_in = (const float*)d_in[3];
    const float* emb_out = (const float*)d_in[4];
    const float* enc_Wih = (const float*)d_in[5];
    const float* enc_Whh = (const float*)d_in[6];
    const float* enc_bih = (const float*)d_in[7];
    const float* enc_bhh = (const float*)d_in[8];
    const float* dec_Wih = (const float*)d_in[9];
    const float* dec_Whh = (const float*)d_in[10];
    const float* dec_bih = (const float*)d_in[11];
    const float* dec_bhh = (const float*)d_in[12];
    const float* attn_W = (const float*)d_in[13];
    const float* attn_b = (const float*)d_in[14];
    const float* out_W = (const float*)d_in[15];
    const float* out_b = (const float*)d_in[16];
    float* out = (float*)d_out;

    char* p = (char*)d_ws;
    auto alloc = [&](size_t bytes) {
        char* r = p;
        p += (bytes + 255) & ~(size_t)255;
        return r;
    };
    u16* A_enc3 = (u16*)alloc((size_t)2048 * 1536 * 2);
    u16* A_dec3 = (u16*)alloc((size_t)2048 * 1536 * 2);
    u16* W_e3 = (u16*)alloc((size_t)4096 * 1536 * 2);
    u16* W_d3 = (u16*)alloc((size_t)4096 * 1536 * 2);
    u16* Wo = (u16*)alloc((size_t)32000 * 1024 * 2);
    float* enc_pre = (float*)alloc((size_t)2048 * 4096 * 4);
    float* dec_pre = (float*)alloc((size_t)2048 * 4096 * 4);
    float* enc_out = (float*)alloc((size_t)16 * 128 * 1024 * 4);
    u16* a2bf = (u16*)alloc((size_t)2048 * 1024 * 2);
    // zeroed state: h0 | c | a0 (3 x 16K floats contiguous)
    float* h0 = (float*)alloc(16 * 1024 * 4);
    float* c = (float*)alloc(16 * 1024 * 4);
    float* a0 = (float*)alloc(16 * 1024 * 4);
    // zeroed barrier flags: arrE | relE | arrD | relD (4 x 512 x 16 ints contiguous)
    int* barE_a = (int*)alloc((size_t)512 * 16 * 4);
    int* barE_r = (int*)alloc((size_t)512 * 16 * 4);
    int* barD_a = (int*)alloc((size_t)512 * 16 * 4);
    int* barD_r = (int*)alloc((size_t)512 * 16 * 4);
    int* mask2 = (int*)alloc(16 * 128 * 4);

    // Write-once rings for decoder state, aliased onto the A3/W3 staging
    // buffers (dead after the pre-GEMMs; 3 x 8.39MB <= 37.7MB region).
    float* h_ring = (float*)A_enc3;
    float* a_ring = h_ring + (size_t)128 * B_ * H_;
    float* ct_ring = a_ring + (size_t)128 * B_ * H_;

    init_k<<<48, 256, 0, stream>>>(h0, barE_a, mask, mask2);

    split3_rows_k<<<4096, 128, 0, stream>>>(enc_Wih, 512, W_e3, 4096, 1024, 512);
    split3_rows_k<<<4096, 128, 0, stream>>>(dec_Wih, 1536, W_d3, 4096, 1024, 512);
    f32_to_bf16_k<<<32000, 256, 0, stream>>>(out_W, Wo, 32000 * 1024 / 4);
    gather_split_k<<<2048, 128, 0, stream>>>(in_tok, emb_in, A_enc3, 2048);
    gather_split_k<<<2032, 128, 0, stream>>>(out_tok, emb_out, A_dec3, 2032);

    gemm_bt<0><<<dim3(16, 32), 256, 0, stream>>>(A_enc3, W_e3, enc_pre, enc_bih, enc_bhh,
                                                 2048, 4096, 1536);
    gemm_bt<0><<<dim3(16, 32), 256, 0, stream>>>(A_dec3, W_d3, dec_pre, dec_bih, dec_bhh,
                                                 2048, 4096, 1536);

    enc_persist<<<512, 256, 0, stream>>>(enc_pre, enc_Whh, h0, c, enc_out,
                                         barE_a, barE_r);

    dec_persist<<<512, 256, 0, stream>>>(dec_pre, dec_Whh, dec_Wih, attn_W, attn_b,
                                         enc_out, h_ring, a_ring, ct_ring, a0, c,
                                         mask2, a2bf, barD_a, barD_r);

    gemm_bt<1><<<dim3(16, 250), 256, 0, stream>>>(a2bf, Wo, out, out_b, nullptr,
                                                  2048, 32000, 1024);
}